// Round 10
// baseline (800.391 us; speedup 1.0000x reference)
//
#include <hip/hip_runtime.h>
#include <hip/hip_bf16.h>
#include <cstdint>
#include <cstddef>

#define N_NODES 10000
#define N_EDGES 320000
#define N_GRAPHS 64
#define KCHEB 10
#define C_IN 128
#define C_HID 256
#define C_OUTC 128
#define POOL_CHUNK 40

static inline size_t align_up(size_t v, size_t a){ return (v + a - 1) / a * a; }

typedef __attribute__((ext_vector_type(8))) short short8;
typedef __attribute__((ext_vector_type(4))) float f32x4;

__device__ inline float bf2f(unsigned int bits16){
  union{ unsigned int i; float f; } v; v.i = bits16 << 16; return v.f;
}
__device__ inline unsigned short f2bf_bits(float f){
  __hip_bfloat16 h = __float2bfloat16(f);
  return *reinterpret_cast<unsigned short*>(&h);
}

// ---------------- graph setup kernels ----------------

__global__ void k_deg(const int* __restrict__ src, const int* __restrict__ dst,
                      int* __restrict__ deg, int* __restrict__ indeg){
  int e = blockIdx.x*blockDim.x + threadIdx.x;
  if(e < N_EDGES){
    atomicAdd(&deg[src[e]], 1);
    atomicAdd(&indeg[dst[e]], 1);
  }
}

__global__ void k_dis(const int* __restrict__ deg, float* __restrict__ dis){
  int i = blockIdx.x*blockDim.x + threadIdx.x;
  if(i < N_NODES){
    int d = deg[i];
    dis[i] = d > 0 ? rsqrtf((float)d) : 0.f;
  }
}

__global__ void k_edgew(const int* __restrict__ src, const int* __restrict__ dst,
                        const float* __restrict__ dis, float* __restrict__ w){
  int e = blockIdx.x*blockDim.x + threadIdx.x;
  if(e < N_EDGES){
    w[e] = -dis[src[e]] * dis[dst[e]];
  }
}

__global__ __launch_bounds__(1024) void k_scan(const int* __restrict__ cnt,
                                               int* __restrict__ offs,
                                               int* __restrict__ cursor){
  __shared__ int part[1024];
  const int n = N_NODES;
  const int CH = (n + 1023) / 1024;
  int tid = threadIdx.x;
  int base = tid * CH;
  int s = 0;
  for(int i = 0; i < CH; i++){
    int idx = base + i;
    if(idx < n) s += cnt[idx];
  }
  part[tid] = s;
  __syncthreads();
  for(int off = 1; off < 1024; off <<= 1){
    int v = (tid >= off) ? part[tid - off] : 0;
    __syncthreads();
    part[tid] += v;
    __syncthreads();
  }
  int run = (tid == 0) ? 0 : part[tid - 1];
  for(int i = 0; i < CH; i++){
    int idx = base + i;
    if(idx < n){
      offs[idx] = run;
      cursor[idx] = run;
      run += cnt[idx];
    }
  }
  if(tid == 1023) offs[n] = part[1023];
}

__global__ void k_scatter(const int* __restrict__ src, const int* __restrict__ dst,
                          const float* __restrict__ w, int* __restrict__ cursor,
                          int* __restrict__ csr_s, float* __restrict__ csr_w){
  int e = blockIdx.x*blockDim.x + threadIdx.x;
  if(e < N_EDGES){
    int d = dst[e];
    int p = atomicAdd(&cursor[d], 1);
    csr_s[p] = src[e];
    csr_w[p] = w[e];
  }
}

__global__ __launch_bounds__(128) void k_gbounds(const int* __restrict__ batch,
                                                 int* __restrict__ gstart,
                                                 int* __restrict__ gcnt){
  int g = threadIdx.x;
  if(g <= N_GRAPHS){
    int lo = 0, hi = N_NODES;
    while(lo < hi){
      int mid = (lo + hi) >> 1;
      if(batch[mid] < g) lo = mid + 1; else hi = mid;
    }
    gstart[g] = lo;
  }
  __syncthreads();
  if(g < N_GRAPHS) gcnt[g] = gstart[g + 1] - gstart[g];
}

// ---------------- propagation (bf16 state, channel-split, MLP=16) ----------------
// tx_k[i,c] = bf16( alpha * sum_j w_j * Xb[src_j,c] - (Pb ? Pb[i,c] : 0) )
// C=256: grid (N/8, 2); blockIdx.y = channel half -> 2.56 MB gather working set
// per phase (fits 4 MB per-XCD L2). Half-wave per node, 32 lanes x 4 ch (uint2),
// 16 gathers in flight per edge batch.

__global__ __launch_bounds__(256) void k_prop256(const __hip_bfloat16* __restrict__ Xb,
                                                 const __hip_bfloat16* __restrict__ Pb,
                                                 __hip_bfloat16* __restrict__ tx,
                                                 const int* __restrict__ csr_s,
                                                 const float* __restrict__ csr_w,
                                                 const int* __restrict__ offs,
                                                 float alpha){
  const int stride = KCHEB * C_HID;
  int hl   = threadIdx.x & 31;
  int b32  = threadIdx.x & 32;
  int node = blockIdx.x * 8 + (threadIdx.x >> 5);
  int coff = blockIdx.y * 128;
  int j0 = offs[node], j1 = offs[node + 1];
  float a[4] = {};
  const __hip_bfloat16* __restrict__ gbase = Xb + coff + hl * 4;
  int j = j0;
  for(; j + 15 < j1; j += 16){
    int   sv = csr_s[j + (hl & 15)];
    float wv = csr_w[j + (hl & 15)];
    uint2 v[16];
#pragma unroll
    for(int i = 0; i < 16; i++){
      int si = __shfl(sv, b32 + i);
      v[i] = *(const uint2*)(gbase + (size_t)si * stride);
    }
#pragma unroll
    for(int i = 0; i < 16; i++){
      float wi = __shfl(wv, b32 + i);
      a[0] += wi * bf2f(v[i].x & 0xffffu); a[1] += wi * bf2f(v[i].x >> 16);
      a[2] += wi * bf2f(v[i].y & 0xffffu); a[3] += wi * bf2f(v[i].y >> 16);
    }
  }
  for(; j + 3 < j1; j += 4){
    int   sv = csr_s[j + (hl & 3)];
    float wv = csr_w[j + (hl & 3)];
    uint2 v[4];
#pragma unroll
    for(int i = 0; i < 4; i++){
      int si = __shfl(sv, b32 + i);
      v[i] = *(const uint2*)(gbase + (size_t)si * stride);
    }
#pragma unroll
    for(int i = 0; i < 4; i++){
      float wi = __shfl(wv, b32 + i);
      a[0] += wi * bf2f(v[i].x & 0xffffu); a[1] += wi * bf2f(v[i].x >> 16);
      a[2] += wi * bf2f(v[i].y & 0xffffu); a[3] += wi * bf2f(v[i].y >> 16);
    }
  }
  for(; j < j1; j++){
    float w0 = csr_w[j];
    uint2 v0 = *(const uint2*)(gbase + (size_t)csr_s[j] * stride);
    a[0] += w0 * bf2f(v0.x & 0xffffu); a[1] += w0 * bf2f(v0.x >> 16);
    a[2] += w0 * bf2f(v0.y & 0xffffu); a[3] += w0 * bf2f(v0.y >> 16);
  }
  float r0 = alpha * a[0], r1 = alpha * a[1], r2 = alpha * a[2], r3 = alpha * a[3];
  size_t off = (size_t)node * stride + coff + hl * 4;
  if(Pb){
    uint2 pv = *(const uint2*)(Pb + off);
    r0 -= bf2f(pv.x & 0xffffu); r1 -= bf2f(pv.x >> 16);
    r2 -= bf2f(pv.y & 0xffffu); r3 -= bf2f(pv.y >> 16);
  }
  uint2 ob;
  ob.x = (unsigned)f2bf_bits(r0) | ((unsigned)f2bf_bits(r1) << 16);
  ob.y = (unsigned)f2bf_bits(r2) | ((unsigned)f2bf_bits(r3) << 16);
  *(uint2*)(tx + off) = ob;
}

// C=128: working set already 2.56 MB; half-wave per node, 32 lanes x 4 ch, MLP=16.
__global__ __launch_bounds__(256) void k_prop128(const __hip_bfloat16* __restrict__ Xb,
                                                 const __hip_bfloat16* __restrict__ Pb,
                                                 __hip_bfloat16* __restrict__ tx,
                                                 const int* __restrict__ csr_s,
                                                 const float* __restrict__ csr_w,
                                                 const int* __restrict__ offs,
                                                 float alpha){
  const int stride = KCHEB * C_IN;
  int hl   = threadIdx.x & 31;
  int b32  = threadIdx.x & 32;
  int node = blockIdx.x * 8 + (threadIdx.x >> 5);
  int j0 = offs[node], j1 = offs[node + 1];
  float a[4] = {};
  const __hip_bfloat16* __restrict__ gbase = Xb + hl * 4;
  int j = j0;
  for(; j + 15 < j1; j += 16){
    int   sv = csr_s[j + (hl & 15)];
    float wv = csr_w[j + (hl & 15)];
    uint2 v[16];
#pragma unroll
    for(int i = 0; i < 16; i++){
      int si = __shfl(sv, b32 + i);
      v[i] = *(const uint2*)(gbase + (size_t)si * stride);
    }
#pragma unroll
    for(int i = 0; i < 16; i++){
      float wi = __shfl(wv, b32 + i);
      a[0] += wi * bf2f(v[i].x & 0xffffu); a[1] += wi * bf2f(v[i].x >> 16);
      a[2] += wi * bf2f(v[i].y & 0xffffu); a[3] += wi * bf2f(v[i].y >> 16);
    }
  }
  for(; j + 3 < j1; j += 4){
    int   sv = csr_s[j + (hl & 3)];
    float wv = csr_w[j + (hl & 3)];
    uint2 v[4];
#pragma unroll
    for(int i = 0; i < 4; i++){
      int si = __shfl(sv, b32 + i);
      v[i] = *(const uint2*)(gbase + (size_t)si * stride);
    }
#pragma unroll
    for(int i = 0; i < 4; i++){
      float wi = __shfl(wv, b32 + i);
      a[0] += wi * bf2f(v[i].x & 0xffffu); a[1] += wi * bf2f(v[i].x >> 16);
      a[2] += wi * bf2f(v[i].y & 0xffffu); a[3] += wi * bf2f(v[i].y >> 16);
    }
  }
  for(; j < j1; j++){
    float w0 = csr_w[j];
    uint2 v0 = *(const uint2*)(gbase + (size_t)csr_s[j] * stride);
    a[0] += w0 * bf2f(v0.x & 0xffffu); a[1] += w0 * bf2f(v0.x >> 16);
    a[2] += w0 * bf2f(v0.y & 0xffffu); a[3] += w0 * bf2f(v0.y >> 16);
  }
  float r0 = alpha * a[0], r1 = alpha * a[1], r2 = alpha * a[2], r3 = alpha * a[3];
  size_t off = (size_t)node * stride + hl * 4;
  if(Pb){
    uint2 pv = *(const uint2*)(Pb + off);
    r0 -= bf2f(pv.x & 0xffffu); r1 -= bf2f(pv.x >> 16);
    r2 -= bf2f(pv.y & 0xffffu); r3 -= bf2f(pv.y >> 16);
  }
  uint2 ob;
  ob.x = (unsigned)f2bf_bits(r0) | ((unsigned)f2bf_bits(r1) << 16);
  ob.y = (unsigned)f2bf_bits(r2) | ((unsigned)f2bf_bits(r3) << 16);
  *(uint2*)(tx + off) = ob;
}

// fp32 [rows][C] -> bf16 strided slot
template<int C>
__global__ void k_f2bf(const float* __restrict__ X, __hip_bfloat16* __restrict__ tx,
                       int tx_stride){
  int idx = blockIdx.x * blockDim.x + threadIdx.x;
  const int GPR = C / 4;
  if(idx < N_NODES * GPR){
    int r = idx / GPR;
    int c = (idx - r * GPR) * 4;
    float4 v = *(const float4*)(X + (size_t)r * C + c);
    uint2 ob;
    ob.x = (unsigned)f2bf_bits(v.x) | ((unsigned)f2bf_bits(v.y) << 16);
    ob.y = (unsigned)f2bf_bits(v.z) | ((unsigned)f2bf_bits(v.w) << 16);
    *(uint2*)(tx + (size_t)r * tx_stride + c) = ob;
  }
}

// weight transpose + bf16: WT[o][kc] = W[kc][o]
__global__ void k_wt(const float* __restrict__ W, __hip_bfloat16* __restrict__ WT, int Ktot){
  int idx = blockIdx.x * blockDim.x + threadIdx.x;
  if(idx < Ktot * 256){
    int o = idx / Ktot;
    int kc = idx - o * Ktot;
    WT[idx] = __float2bfloat16(W[(size_t)kc * 256 + o]);
  }
}

// ---------------- MFMA GEMM, XCD-pinned swizzle ----------------
// H[M][256] = relu( A[M][Ktot](bf16) @ BT[256][Ktot](bf16)^T + bias )
// 64M x 64N tiles; the 4 col-chunks of a row-group sit on ONE XCD.

__global__ __launch_bounds__(256) void k_gemm_f(const __hip_bfloat16* __restrict__ A,
                                                const __hip_bfloat16* __restrict__ BT,
                                                const float* __restrict__ bias,
                                                float* __restrict__ H,
                                                int M, int Ktot){
  int b = blockIdx.x;
  int xcd = b & 7;
  int l = b >> 3;
  int m = xcd + 8 * (l >> 2);
  int n = l & 3;
  if(m * 64 >= M) return;
  int row0 = m * 64, col0 = n * 64;

  __shared__ short As[64 * 64];
  __shared__ short Bs[64 * 64];
  int tid = threadIdx.x;
  int lane = tid & 63;
  int wave = tid >> 6;
  int l15 = lane & 15;
  int quad = lane >> 4;
  int wm = (wave & 1) * 32;
  int wn = (wave >> 1) * 32;

  f32x4 acc[2][2] = {};

  for(int k0 = 0; k0 < Ktot; k0 += 64){
#pragma unroll
    for(int i = 0; i < 2; i++){
      int e = tid + i * 256;
      int r = e >> 3, g = e & 7;
      uint4 v = make_uint4(0u, 0u, 0u, 0u);
      int gr = row0 + r;
      if(gr < M) v = *(const uint4*)(A + (size_t)gr * Ktot + k0 + g * 8);
      *(uint4*)(As + r * 64 + ((g ^ (r & 7)) * 8)) = v;
    }
#pragma unroll
    for(int i = 0; i < 2; i++){
      int e = tid + i * 256;
      int nn = e >> 3, g = e & 7;
      uint4 v = *(const uint4*)(BT + (size_t)(col0 + nn) * Ktot + k0 + g * 8);
      *(uint4*)(Bs + nn * 64 + ((g ^ (nn & 7)) * 8)) = v;
    }
    __syncthreads();
#pragma unroll
    for(int kk = 0; kk < 64; kk += 32){
      int g = (kk >> 3) + quad;
      short8 a[2], bb[2];
#pragma unroll
      for(int mi = 0; mi < 2; mi++){
        int r = wm + mi * 16 + l15;
        a[mi] = *(const short8*)(As + r * 64 + ((g ^ (r & 7)) * 8));
      }
#pragma unroll
      for(int ni = 0; ni < 2; ni++){
        int nn = wn + ni * 16 + l15;
        bb[ni] = *(const short8*)(Bs + nn * 64 + ((g ^ (nn & 7)) * 8));
      }
#pragma unroll
      for(int mi = 0; mi < 2; mi++)
#pragma unroll
        for(int ni = 0; ni < 2; ni++)
          acc[mi][ni] = __builtin_amdgcn_mfma_f32_16x16x32_bf16(a[mi], bb[ni], acc[mi][ni], 0, 0, 0);
    }
    __syncthreads();
  }

#pragma unroll
  for(int mi = 0; mi < 2; mi++){
#pragma unroll
    for(int ni = 0; ni < 2; ni++){
      int gcol = col0 + wn + ni * 16 + l15;
      float bv = bias[gcol];
#pragma unroll
      for(int r = 0; r < 4; r++){
        int grow = row0 + wm + mi * 16 + quad * 4 + r;
        if(grow < M){
          float v = fmaxf(acc[mi][ni][r] + bv, 0.f);
          H[(size_t)grow * C_HID + gcol] = v;
        }
      }
    }
  }
}

// ---------------- pooling + head ----------------

__global__ __launch_bounds__(256) void k_pool2(const float* __restrict__ h,
                                               const int* __restrict__ batch,
                                               float* __restrict__ gsum){
  int c  = threadIdx.x;
  int n0 = blockIdx.x * POOL_CHUNK;
  int n1 = n0 + POOL_CHUNK;
  if(n1 > N_NODES) n1 = N_NODES;
  if(n0 >= n1) return;
  float acc = 0.f;
  int cur = batch[n0];
  for(int n = n0; n < n1; n++){
    int g = batch[n];
    if(g != cur){
      atomicAdd(&gsum[cur * C_HID + c], acc);
      acc = 0.f;
      cur = g;
    }
    acc += h[(size_t)n * C_HID + c];
  }
  atomicAdd(&gsum[cur * C_HID + c], acc);
}

__global__ __launch_bounds__(128) void k_final(const float* __restrict__ gsum,
                                               const int* __restrict__ gcnt,
                                               const float* __restrict__ Wout,
                                               const float* __restrict__ bout,
                                               float* __restrict__ out){
  int g = blockIdx.x;
  int o = threadIdx.x;
  float inv = 1.f / fmaxf((float)gcnt[g], 1.f);
  float acc = bout[o];
  for(int c = 0; c < C_HID; c++) acc += gsum[g * C_HID + c] * inv * Wout[c * C_OUTC + o];
  out[g * C_OUTC + o] = acc;
}

// ---------------- host ----------------

extern "C" void kernel_launch(void* const* d_in, const int* in_sizes, int n_in,
                              void* d_out, int out_size, void* d_ws, size_t ws_size,
                              hipStream_t stream){
  const float* x    = (const float*)d_in[0];
  const float* W0   = (const float*)d_in[1];
  const float* b0   = (const float*)d_in[2];
  const float* W1   = (const float*)d_in[3];
  const float* b1   = (const float*)d_in[4];
  const float* W2   = (const float*)d_in[5];
  const float* b2   = (const float*)d_in[6];
  const float* Wout = (const float*)d_in[7];
  const float* bout = (const float*)d_in[8];
  const int*   ei   = (const int*)d_in[9];
  const int*   batch= (const int*)d_in[10];
  const int* src = ei;
  const int* dst = ei + N_EDGES;
  float* out = (float*)d_out;

  char* p = (char*)d_ws;
  auto alloc = [&](size_t bytes)->char*{ char* r = p; p += align_up(bytes, 256); return r; };

  int*   deg    = (int*)  alloc(N_NODES * 4);
  int*   indeg  = (int*)  alloc(N_NODES * 4);
  int*   offs   = (int*)  alloc((N_NODES + 1) * 4);
  int*   cursor = (int*)  alloc(N_NODES * 4);
  float* dis    = (float*)alloc(N_NODES * 4);
  float* w_e    = (float*)alloc(N_EDGES * 4);
  int*   csr_s  = (int*)  alloc(N_EDGES * 4);
  float* csr_w  = (float*)alloc(N_EDGES * 4);
  int*   gcnt   = (int*)  alloc(N_GRAPHS * 4);
  int*   gstart = (int*)  alloc((N_GRAPHS + 1) * 4);
  float* gsum   = (float*)alloc(N_GRAPHS * C_HID * 4);

  __hip_bfloat16* txall = (__hip_bfloat16*)alloc((size_t)N_NODES * (KCHEB * C_HID) * 2);
  __hip_bfloat16* WT0   = (__hip_bfloat16*)alloc((size_t)KCHEB * C_IN  * C_HID * 2);
  __hip_bfloat16* WT1   = (__hip_bfloat16*)alloc((size_t)KCHEB * C_HID * C_HID * 2);
  __hip_bfloat16* WT2   = (__hip_bfloat16*)alloc((size_t)KCHEB * C_HID * C_HID * 2);
  float* Hb = (float*)alloc((size_t)N_NODES * C_HID * 4);

  hipMemsetAsync(deg,   0, N_NODES * 4, stream);
  hipMemsetAsync(indeg, 0, N_NODES * 4, stream);
  hipMemsetAsync(gsum,  0, N_GRAPHS * C_HID * 4, stream);

  const int TB = 256;
  int egrid = (N_EDGES + TB - 1) / TB;
  int ngrid = (N_NODES + TB - 1) / TB;

  k_deg<<<egrid, TB, 0, stream>>>(src, dst, deg, indeg);
  k_dis<<<ngrid, TB, 0, stream>>>(deg, dis);
  k_edgew<<<egrid, TB, 0, stream>>>(src, dst, dis, w_e);
  k_scan<<<1, 1024, 0, stream>>>(indeg, offs, cursor);
  k_scatter<<<egrid, TB, 0, stream>>>(src, dst, w_e, cursor, csr_s, csr_w);
  k_gbounds<<<1, 128, 0, stream>>>(batch, gstart, gcnt);

  {
    int n0 = KCHEB * C_IN  * C_HID;
    int n1 = KCHEB * C_HID * C_HID;
    k_wt<<<(n0 + TB - 1) / TB, TB, 0, stream>>>(W0, WT0, KCHEB * C_IN);
    k_wt<<<(n1 + TB - 1) / TB, TB, 0, stream>>>(W1, WT1, KCHEB * C_HID);
    k_wt<<<(n1 + TB - 1) / TB, TB, 0, stream>>>(W2, WT2, KCHEB * C_HID);
  }

  const int K128 = KCHEB * C_IN;   // 1280
  const int K256 = KCHEB * C_HID;  // 2560
  const int GEMM_BLOCKS = 640;

  // ---- layer 1 (Cin=128) ----
  {
    int ng = N_NODES * (C_IN / 4);
    k_f2bf<C_IN><<<(ng + TB - 1) / TB, TB, 0, stream>>>(x, txall, K128);
    for(int k = 1; k < KCHEB; k++){
      const __hip_bfloat16* Xb = txall + (size_t)(k - 1) * C_IN;
      const __hip_bfloat16* Pb = (k >= 2) ? txall + (size_t)(k - 2) * C_IN : nullptr;
      __hip_bfloat16* tx = txall + (size_t)k * C_IN;
      k_prop128<<<N_NODES / 8, 256, 0, stream>>>(Xb, Pb, tx, csr_s, csr_w, offs,
                                                 k == 1 ? 1.f : 2.f);
    }
    k_gemm_f<<<GEMM_BLOCKS, 256, 0, stream>>>(txall, WT0, b0, Hb, N_NODES, K128);
    int ng2 = N_NODES * (C_HID / 4);
    k_f2bf<C_HID><<<(ng2 + TB - 1) / TB, TB, 0, stream>>>(Hb, txall, K256);
  }

  // ---- layers 2,3 (Cin=256) ----
  for(int layer = 1; layer < 3; layer++){
    const __hip_bfloat16* WT = (layer == 1) ? WT1 : WT2;
    const float* b = (layer == 1) ? b1 : b2;
    for(int k = 1; k < KCHEB; k++){
      const __hip_bfloat16* Xb = txall + (size_t)(k - 1) * C_HID;
      const __hip_bfloat16* Pb = (k >= 2) ? txall + (size_t)(k - 2) * C_HID : nullptr;
      __hip_bfloat16* tx = txall + (size_t)k * C_HID;
      k_prop256<<<dim3(N_NODES / 8, 2), 256, 0, stream>>>(Xb, Pb, tx, csr_s, csr_w, offs,
                                                          k == 1 ? 1.f : 2.f);
    }
    k_gemm_f<<<GEMM_BLOCKS, 256, 0, stream>>>(txall, WT, b, Hb, N_NODES, K256);
    if(layer == 1){
      int ng2 = N_NODES * (C_HID / 4);
      k_f2bf<C_HID><<<(ng2 + TB - 1) / TB, TB, 0, stream>>>(Hb, txall, K256);
    }
  }

  k_pool2<<<(N_NODES + POOL_CHUNK - 1) / POOL_CHUNK, 256, 0, stream>>>(Hb, batch, gsum);
  k_final<<<N_GRAPHS, C_OUTC, 0, stream>>>(gsum, gcnt, Wout, bout, out);
}

// Round 11
// 692.162 us; speedup vs baseline: 1.1564x; 1.1564x over previous
//
#include <hip/hip_runtime.h>
#include <hip/hip_bf16.h>
#include <cstdint>
#include <cstddef>

#define N_NODES 10000
#define N_EDGES 320000
#define N_GRAPHS 64
#define KCHEB 10
#define C_IN 128
#define C_HID 256
#define C_OUTC 128
#define POOL_CHUNK 40

static inline size_t align_up(size_t v, size_t a){ return (v + a - 1) / a * a; }

typedef __attribute__((ext_vector_type(8))) short short8;
typedef __attribute__((ext_vector_type(4))) float f32x4;

__device__ inline float bf2f(unsigned int bits16){
  union{ unsigned int i; float f; } v; v.i = bits16 << 16; return v.f;
}
__device__ inline unsigned short f2bf_bits(float f){
  __hip_bfloat16 h = __float2bfloat16(f);
  return *reinterpret_cast<unsigned short*>(&h);
}

// ---------------- graph setup kernels ----------------

__global__ void k_deg(const int* __restrict__ src, const int* __restrict__ dst,
                      int* __restrict__ deg, int* __restrict__ indeg){
  int e = blockIdx.x*blockDim.x + threadIdx.x;
  if(e < N_EDGES){
    atomicAdd(&deg[src[e]], 1);
    atomicAdd(&indeg[dst[e]], 1);
  }
}

__global__ void k_dis(const int* __restrict__ deg, float* __restrict__ dis){
  int i = blockIdx.x*blockDim.x + threadIdx.x;
  if(i < N_NODES){
    int d = deg[i];
    dis[i] = d > 0 ? rsqrtf((float)d) : 0.f;
  }
}

__global__ void k_edgew(const int* __restrict__ src, const int* __restrict__ dst,
                        const float* __restrict__ dis, float* __restrict__ w){
  int e = blockIdx.x*blockDim.x + threadIdx.x;
  if(e < N_EDGES){
    w[e] = -dis[src[e]] * dis[dst[e]];
  }
}

__global__ __launch_bounds__(1024) void k_scan(const int* __restrict__ cnt,
                                               int* __restrict__ offs,
                                               int* __restrict__ cursor){
  __shared__ int part[1024];
  const int n = N_NODES;
  const int CH = (n + 1023) / 1024;
  int tid = threadIdx.x;
  int base = tid * CH;
  int s = 0;
  for(int i = 0; i < CH; i++){
    int idx = base + i;
    if(idx < n) s += cnt[idx];
  }
  part[tid] = s;
  __syncthreads();
  for(int off = 1; off < 1024; off <<= 1){
    int v = (tid >= off) ? part[tid - off] : 0;
    __syncthreads();
    part[tid] += v;
    __syncthreads();
  }
  int run = (tid == 0) ? 0 : part[tid - 1];
  for(int i = 0; i < CH; i++){
    int idx = base + i;
    if(idx < n){
      offs[idx] = run;
      cursor[idx] = run;
      run += cnt[idx];
    }
  }
  if(tid == 1023) offs[n] = part[1023];
}

__global__ void k_scatter(const int* __restrict__ src, const int* __restrict__ dst,
                          const float* __restrict__ w, int* __restrict__ cursor,
                          int* __restrict__ csr_s, float* __restrict__ csr_w){
  int e = blockIdx.x*blockDim.x + threadIdx.x;
  if(e < N_EDGES){
    int d = dst[e];
    int p = atomicAdd(&cursor[d], 1);
    csr_s[p] = src[e];
    csr_w[p] = w[e];
  }
}

__global__ __launch_bounds__(128) void k_gbounds(const int* __restrict__ batch,
                                                 int* __restrict__ gstart,
                                                 int* __restrict__ gcnt){
  int g = threadIdx.x;
  if(g <= N_GRAPHS){
    int lo = 0, hi = N_NODES;
    while(lo < hi){
      int mid = (lo + hi) >> 1;
      if(batch[mid] < g) lo = mid + 1; else hi = mid;
    }
    gstart[g] = lo;
  }
  __syncthreads();
  if(g < N_GRAPHS) gcnt[g] = gstart[g + 1] - gstart[g];
}

// ---------------- propagation (round-9 structure: bf16 state, uint4, MLP=8) ----

__device__ inline void fma8(float* a, uint4 v, float w){
  a[0] += w * bf2f(v.x & 0xffffu); a[1] += w * bf2f(v.x >> 16);
  a[2] += w * bf2f(v.y & 0xffffu); a[3] += w * bf2f(v.y >> 16);
  a[4] += w * bf2f(v.z & 0xffffu); a[5] += w * bf2f(v.z >> 16);
  a[6] += w * bf2f(v.w & 0xffffu); a[7] += w * bf2f(v.w >> 16);
}

__global__ __launch_bounds__(256) void k_prop256(const __hip_bfloat16* __restrict__ Xb,
                                                 const __hip_bfloat16* __restrict__ Pb,
                                                 __hip_bfloat16* __restrict__ tx,
                                                 const int* __restrict__ csr_s,
                                                 const float* __restrict__ csr_w,
                                                 const int* __restrict__ offs,
                                                 float alpha){
  const int stride = KCHEB * C_HID;
  int hl   = threadIdx.x & 31;
  int b32  = threadIdx.x & 32;
  int node = blockIdx.x * 8 + (threadIdx.x >> 5);
  int j0 = offs[node], j1 = offs[node + 1];
  float a[8] = {};
  const __hip_bfloat16* __restrict__ gbase = Xb + hl * 8;
  int j = j0;
  int sv = 0; float wv = 0.f;
  bool have = (j + 7 < j1);
  if(have){ sv = csr_s[j + (hl & 7)]; wv = csr_w[j + (hl & 7)]; }
  while(have){
    int jn = j + 8;
    bool more = (jn + 7 < j1);
    int sv2 = 0; float wv2 = 0.f;
    if(more){ sv2 = csr_s[jn + (hl & 7)]; wv2 = csr_w[jn + (hl & 7)]; }
    uint4 v[8];
#pragma unroll
    for(int i = 0; i < 8; i++){
      int si = __shfl(sv, b32 + i);
      v[i] = *(const uint4*)(gbase + (size_t)si * stride);
    }
#pragma unroll
    for(int i = 0; i < 8; i++){
      float wi = __shfl(wv, b32 + i);
      fma8(a, v[i], wi);
    }
    sv = sv2; wv = wv2; j = jn; have = more;
  }
  for(; j < j1; j++){
    uint4 v0 = *(const uint4*)(gbase + (size_t)csr_s[j] * stride);
    fma8(a, v0, csr_w[j]);
  }
  float r[8];
#pragma unroll
  for(int i = 0; i < 8; i++) r[i] = alpha * a[i];
  size_t off = (size_t)node * stride + hl * 8;
  if(Pb){
    uint4 pv = *(const uint4*)(Pb + off);
    r[0] -= bf2f(pv.x & 0xffffu); r[1] -= bf2f(pv.x >> 16);
    r[2] -= bf2f(pv.y & 0xffffu); r[3] -= bf2f(pv.y >> 16);
    r[4] -= bf2f(pv.z & 0xffffu); r[5] -= bf2f(pv.z >> 16);
    r[6] -= bf2f(pv.w & 0xffffu); r[7] -= bf2f(pv.w >> 16);
  }
  uint4 ob;
  ob.x = (unsigned)f2bf_bits(r[0]) | ((unsigned)f2bf_bits(r[1]) << 16);
  ob.y = (unsigned)f2bf_bits(r[2]) | ((unsigned)f2bf_bits(r[3]) << 16);
  ob.z = (unsigned)f2bf_bits(r[4]) | ((unsigned)f2bf_bits(r[5]) << 16);
  ob.w = (unsigned)f2bf_bits(r[6]) | ((unsigned)f2bf_bits(r[7]) << 16);
  *(uint4*)(tx + off) = ob;
}

__global__ __launch_bounds__(256) void k_prop128(const __hip_bfloat16* __restrict__ Xb,
                                                 const __hip_bfloat16* __restrict__ Pb,
                                                 __hip_bfloat16* __restrict__ tx,
                                                 const int* __restrict__ csr_s,
                                                 const float* __restrict__ csr_w,
                                                 const int* __restrict__ offs,
                                                 float alpha){
  const int stride = KCHEB * C_IN;
  int hl   = threadIdx.x & 31;
  int b32  = threadIdx.x & 32;
  int node = blockIdx.x * 8 + (threadIdx.x >> 5);
  int j0 = offs[node], j1 = offs[node + 1];
  float a[4] = {};
  const __hip_bfloat16* __restrict__ gbase = Xb + hl * 4;
  int j = j0;
  int sv = 0; float wv = 0.f;
  bool have = (j + 7 < j1);
  if(have){ sv = csr_s[j + (hl & 7)]; wv = csr_w[j + (hl & 7)]; }
  while(have){
    int jn = j + 8;
    bool more = (jn + 7 < j1);
    int sv2 = 0; float wv2 = 0.f;
    if(more){ sv2 = csr_s[jn + (hl & 7)]; wv2 = csr_w[jn + (hl & 7)]; }
    uint2 v[8];
#pragma unroll
    for(int i = 0; i < 8; i++){
      int si = __shfl(sv, b32 + i);
      v[i] = *(const uint2*)(gbase + (size_t)si * stride);
    }
#pragma unroll
    for(int i = 0; i < 8; i++){
      float wi = __shfl(wv, b32 + i);
      a[0] += wi * bf2f(v[i].x & 0xffffu); a[1] += wi * bf2f(v[i].x >> 16);
      a[2] += wi * bf2f(v[i].y & 0xffffu); a[3] += wi * bf2f(v[i].y >> 16);
    }
    sv = sv2; wv = wv2; j = jn; have = more;
  }
  for(; j < j1; j++){
    float w0 = csr_w[j];
    uint2 v0 = *(const uint2*)(gbase + (size_t)csr_s[j] * stride);
    a[0] += w0 * bf2f(v0.x & 0xffffu); a[1] += w0 * bf2f(v0.x >> 16);
    a[2] += w0 * bf2f(v0.y & 0xffffu); a[3] += w0 * bf2f(v0.y >> 16);
  }
  float r0 = alpha * a[0], r1 = alpha * a[1], r2 = alpha * a[2], r3 = alpha * a[3];
  size_t off = (size_t)node * stride + hl * 4;
  if(Pb){
    uint2 pv = *(const uint2*)(Pb + off);
    r0 -= bf2f(pv.x & 0xffffu); r1 -= bf2f(pv.x >> 16);
    r2 -= bf2f(pv.y & 0xffffu); r3 -= bf2f(pv.y >> 16);
  }
  uint2 ob;
  ob.x = (unsigned)f2bf_bits(r0) | ((unsigned)f2bf_bits(r1) << 16);
  ob.y = (unsigned)f2bf_bits(r2) | ((unsigned)f2bf_bits(r3) << 16);
  *(uint2*)(tx + off) = ob;
}

// fp32 [rows][C] -> bf16 strided slot
template<int C>
__global__ void k_f2bf(const float* __restrict__ X, __hip_bfloat16* __restrict__ tx,
                       int tx_stride){
  int idx = blockIdx.x * blockDim.x + threadIdx.x;
  const int GPR = C / 4;
  if(idx < N_NODES * GPR){
    int r = idx / GPR;
    int c = (idx - r * GPR) * 4;
    float4 v = *(const float4*)(X + (size_t)r * C + c);
    uint2 ob;
    ob.x = (unsigned)f2bf_bits(v.x) | ((unsigned)f2bf_bits(v.y) << 16);
    ob.y = (unsigned)f2bf_bits(v.z) | ((unsigned)f2bf_bits(v.w) << 16);
    *(uint2*)(tx + (size_t)r * tx_stride + c) = ob;
  }
}

// weight transpose + bf16: WT[o][kc] = W[kc][o]
__global__ void k_wt(const float* __restrict__ W, __hip_bfloat16* __restrict__ WT, int Ktot){
  int idx = blockIdx.x * blockDim.x + threadIdx.x;
  if(idx < Ktot * 256){
    int o = idx / Ktot;
    int kc = idx - o * Ktot;
    WT[idx] = __float2bfloat16(W[(size_t)kc * 256 + o]);
  }
}

// ---------------- MFMA GEMM, XCD-pinned, double-buffered LDS ----------------
// H[M][256] = relu( A[M][Ktot](bf16) @ BT[256][Ktot](bf16)^T + bias )
// 64M x 64N tiles; ping-pong LDS: global loads for tile k+1 issued before the
// MFMAs of tile k, so the load wait overlaps compute + barrier.

__global__ __launch_bounds__(256) void k_gemm_f(const __hip_bfloat16* __restrict__ A,
                                                const __hip_bfloat16* __restrict__ BT,
                                                const float* __restrict__ bias,
                                                float* __restrict__ H,
                                                int M, int Ktot){
  int b = blockIdx.x;
  int xcd = b & 7;
  int l = b >> 3;
  int m = xcd + 8 * (l >> 2);
  int n = l & 3;
  if(m * 64 >= M) return;
  int row0 = m * 64, col0 = n * 64;

  __shared__ short As[2][64 * 64];
  __shared__ short Bs[2][64 * 64];
  int tid = threadIdx.x;
  int lane = tid & 63;
  int wave = tid >> 6;
  int l15 = lane & 15;
  int quad = lane >> 4;
  int wm = (wave & 1) * 32;
  int wn = (wave >> 1) * 32;

  int e0 = tid, e1 = tid + 256;
  int r0 = e0 >> 3, g0 = e0 & 7;
  int r1 = e1 >> 3, g1 = e1 & 7;
  int gr0 = row0 + r0, gr1 = row0 + r1;
  int sa0 = r0 * 64 + ((g0 ^ (r0 & 7)) * 8);
  int sa1 = r1 * 64 + ((g1 ^ (r1 & 7)) * 8);

  f32x4 acc[2][2] = {};
  uint4 av0, av1, bv0, bv1;

  auto load = [&](int k0){
    av0 = (gr0 < M) ? *(const uint4*)(A + (size_t)gr0 * Ktot + k0 + g0 * 8)
                    : make_uint4(0u, 0u, 0u, 0u);
    av1 = (gr1 < M) ? *(const uint4*)(A + (size_t)gr1 * Ktot + k0 + g1 * 8)
                    : make_uint4(0u, 0u, 0u, 0u);
    bv0 = *(const uint4*)(BT + (size_t)(col0 + r0) * Ktot + k0 + g0 * 8);
    bv1 = *(const uint4*)(BT + (size_t)(col0 + r1) * Ktot + k0 + g1 * 8);
  };
  auto stor = [&](int buf){
    *(uint4*)(&As[buf][sa0]) = av0;
    *(uint4*)(&As[buf][sa1]) = av1;
    *(uint4*)(&Bs[buf][sa0]) = bv0;
    *(uint4*)(&Bs[buf][sa1]) = bv1;
  };

  load(0);
  stor(0);
  __syncthreads();
  int nk = Ktot >> 6;
  for(int it = 0; it < nk; it++){
    int cur = it & 1;
    if(it + 1 < nk) load((it + 1) << 6);   // in flight during MFMAs
#pragma unroll
    for(int kk = 0; kk < 64; kk += 32){
      int g = (kk >> 3) + quad;
      short8 a[2], bb[2];
#pragma unroll
      for(int mi = 0; mi < 2; mi++){
        int r = wm + mi * 16 + l15;
        a[mi] = *(const short8*)(&As[cur][r * 64 + ((g ^ (r & 7)) * 8)]);
      }
#pragma unroll
      for(int ni = 0; ni < 2; ni++){
        int nn = wn + ni * 16 + l15;
        bb[ni] = *(const short8*)(&Bs[cur][nn * 64 + ((g ^ (nn & 7)) * 8)]);
      }
#pragma unroll
      for(int mi = 0; mi < 2; mi++)
#pragma unroll
        for(int ni = 0; ni < 2; ni++)
          acc[mi][ni] = __builtin_amdgcn_mfma_f32_16x16x32_bf16(a[mi], bb[ni], acc[mi][ni], 0, 0, 0);
    }
    if(it + 1 < nk){
      __syncthreads();          // all reads of buf[cur^1] (from it-1) complete
      stor(cur ^ 1);
      __syncthreads();          // stores visible before next iteration's reads
    }
  }

#pragma unroll
  for(int mi = 0; mi < 2; mi++){
#pragma unroll
    for(int ni = 0; ni < 2; ni++){
      int gcol = col0 + wn + ni * 16 + l15;
      float bv = bias[gcol];
#pragma unroll
      for(int r = 0; r < 4; r++){
        int grow = row0 + wm + mi * 16 + quad * 4 + r;
        if(grow < M){
          float v = fmaxf(acc[mi][ni][r] + bv, 0.f);
          H[(size_t)grow * C_HID + gcol] = v;
        }
      }
    }
  }
}

// ---------------- pooling + head ----------------

__global__ __launch_bounds__(256) void k_pool2(const float* __restrict__ h,
                                               const int* __restrict__ batch,
                                               float* __restrict__ gsum){
  int c  = threadIdx.x;
  int n0 = blockIdx.x * POOL_CHUNK;
  int n1 = n0 + POOL_CHUNK;
  if(n1 > N_NODES) n1 = N_NODES;
  if(n0 >= n1) return;
  float acc = 0.f;
  int cur = batch[n0];
  for(int n = n0; n < n1; n++){
    int g = batch[n];
    if(g != cur){
      atomicAdd(&gsum[cur * C_HID + c], acc);
      acc = 0.f;
      cur = g;
    }
    acc += h[(size_t)n * C_HID + c];
  }
  atomicAdd(&gsum[cur * C_HID + c], acc);
}

__global__ __launch_bounds__(128) void k_final(const float* __restrict__ gsum,
                                               const int* __restrict__ gcnt,
                                               const float* __restrict__ Wout,
                                               const float* __restrict__ bout,
                                               float* __restrict__ out){
  int g = blockIdx.x;
  int o = threadIdx.x;
  float inv = 1.f / fmaxf((float)gcnt[g], 1.f);
  float acc = bout[o];
  for(int c = 0; c < C_HID; c++) acc += gsum[g * C_HID + c] * inv * Wout[c * C_OUTC + o];
  out[g * C_OUTC + o] = acc;
}

// ---------------- host ----------------

extern "C" void kernel_launch(void* const* d_in, const int* in_sizes, int n_in,
                              void* d_out, int out_size, void* d_ws, size_t ws_size,
                              hipStream_t stream){
  const float* x    = (const float*)d_in[0];
  const float* W0   = (const float*)d_in[1];
  const float* b0   = (const float*)d_in[2];
  const float* W1   = (const float*)d_in[3];
  const float* b1   = (const float*)d_in[4];
  const float* W2   = (const float*)d_in[5];
  const float* b2   = (const float*)d_in[6];
  const float* Wout = (const float*)d_in[7];
  const float* bout = (const float*)d_in[8];
  const int*   ei   = (const int*)d_in[9];
  const int*   batch= (const int*)d_in[10];
  const int* src = ei;
  const int* dst = ei + N_EDGES;
  float* out = (float*)d_out;

  char* p = (char*)d_ws;
  auto alloc = [&](size_t bytes)->char*{ char* r = p; p += align_up(bytes, 256); return r; };

  int*   deg    = (int*)  alloc(N_NODES * 4);
  int*   indeg  = (int*)  alloc(N_NODES * 4);
  int*   offs   = (int*)  alloc((N_NODES + 1) * 4);
  int*   cursor = (int*)  alloc(N_NODES * 4);
  float* dis    = (float*)alloc(N_NODES * 4);
  float* w_e    = (float*)alloc(N_EDGES * 4);
  int*   csr_s  = (int*)  alloc(N_EDGES * 4);
  float* csr_w  = (float*)alloc(N_EDGES * 4);
  int*   gcnt   = (int*)  alloc(N_GRAPHS * 4);
  int*   gstart = (int*)  alloc((N_GRAPHS + 1) * 4);
  float* gsum   = (float*)alloc(N_GRAPHS * C_HID * 4);

  __hip_bfloat16* txall = (__hip_bfloat16*)alloc((size_t)N_NODES * (KCHEB * C_HID) * 2);
  __hip_bfloat16* WT0   = (__hip_bfloat16*)alloc((size_t)KCHEB * C_IN  * C_HID * 2);
  __hip_bfloat16* WT1   = (__hip_bfloat16*)alloc((size_t)KCHEB * C_HID * C_HID * 2);
  __hip_bfloat16* WT2   = (__hip_bfloat16*)alloc((size_t)KCHEB * C_HID * C_HID * 2);
  float* Hb = (float*)alloc((size_t)N_NODES * C_HID * 4);

  hipMemsetAsync(deg,   0, N_NODES * 4, stream);
  hipMemsetAsync(indeg, 0, N_NODES * 4, stream);
  hipMemsetAsync(gsum,  0, N_GRAPHS * C_HID * 4, stream);

  const int TB = 256;
  int egrid = (N_EDGES + TB - 1) / TB;
  int ngrid = (N_NODES + TB - 1) / TB;

  k_deg<<<egrid, TB, 0, stream>>>(src, dst, deg, indeg);
  k_dis<<<ngrid, TB, 0, stream>>>(deg, dis);
  k_edgew<<<egrid, TB, 0, stream>>>(src, dst, dis, w_e);
  k_scan<<<1, 1024, 0, stream>>>(indeg, offs, cursor);
  k_scatter<<<egrid, TB, 0, stream>>>(src, dst, w_e, cursor, csr_s, csr_w);
  k_gbounds<<<1, 128, 0, stream>>>(batch, gstart, gcnt);

  {
    int n0 = KCHEB * C_IN  * C_HID;
    int n1 = KCHEB * C_HID * C_HID;
    k_wt<<<(n0 + TB - 1) / TB, TB, 0, stream>>>(W0, WT0, KCHEB * C_IN);
    k_wt<<<(n1 + TB - 1) / TB, TB, 0, stream>>>(W1, WT1, KCHEB * C_HID);
    k_wt<<<(n1 + TB - 1) / TB, TB, 0, stream>>>(W2, WT2, KCHEB * C_HID);
  }

  const int K128 = KCHEB * C_IN;   // 1280
  const int K256 = KCHEB * C_HID;  // 2560
  const int GEMM_BLOCKS = 640;

  // ---- layer 1 (Cin=128) ----
  {
    int ng = N_NODES * (C_IN / 4);
    k_f2bf<C_IN><<<(ng + TB - 1) / TB, TB, 0, stream>>>(x, txall, K128);
    for(int k = 1; k < KCHEB; k++){
      const __hip_bfloat16* Xb = txall + (size_t)(k - 1) * C_IN;
      const __hip_bfloat16* Pb = (k >= 2) ? txall + (size_t)(k - 2) * C_IN : nullptr;
      __hip_bfloat16* tx = txall + (size_t)k * C_IN;
      k_prop128<<<N_NODES / 8, 256, 0, stream>>>(Xb, Pb, tx, csr_s, csr_w, offs,
                                                 k == 1 ? 1.f : 2.f);
    }
    k_gemm_f<<<GEMM_BLOCKS, 256, 0, stream>>>(txall, WT0, b0, Hb, N_NODES, K128);
    int ng2 = N_NODES * (C_HID / 4);
    k_f2bf<C_HID><<<(ng2 + TB - 1) / TB, TB, 0, stream>>>(Hb, txall, K256);
  }

  // ---- layers 2,3 (Cin=256) ----
  for(int layer = 1; layer < 3; layer++){
    const __hip_bfloat16* WT = (layer == 1) ? WT1 : WT2;
    const float* b = (layer == 1) ? b1 : b2;
    for(int k = 1; k < KCHEB; k++){
      const __hip_bfloat16* Xb = txall + (size_t)(k - 1) * C_HID;
      const __hip_bfloat16* Pb = (k >= 2) ? txall + (size_t)(k - 2) * C_HID : nullptr;
      __hip_bfloat16* tx = txall + (size_t)k * C_HID;
      k_prop256<<<N_NODES / 8, 256, 0, stream>>>(Xb, Pb, tx, csr_s, csr_w, offs,
                                                 k == 1 ? 1.f : 2.f);
    }
    k_gemm_f<<<GEMM_BLOCKS, 256, 0, stream>>>(txall, WT, b, Hb, N_NODES, K256);
    if(layer == 1){
      int ng2 = N_NODES * (C_HID / 4);
      k_f2bf<C_HID><<<(ng2 + TB - 1) / TB, TB, 0, stream>>>(Hb, txall, K256);
    }
  }

  k_pool2<<<(N_NODES + POOL_CHUNK - 1) / POOL_CHUNK, 256, 0, stream>>>(Hb, batch, gsum);
  k_final<<<N_GRAPHS, C_OUTC, 0, stream>>>(gsum, gcnt, Wout, bout, out);
}

// Round 12
// 685.707 us; speedup vs baseline: 1.1672x; 1.0094x over previous
//
#include <hip/hip_runtime.h>
#include <hip/hip_bf16.h>
#include <cstdint>
#include <cstddef>

#define N_NODES 10000
#define N_EDGES 320000
#define N_GRAPHS 64
#define KCHEB 10
#define C_IN 128
#define C_HID 256
#define C_OUTC 128
#define POOL_CHUNK 40

static inline size_t align_up(size_t v, size_t a){ return (v + a - 1) / a * a; }

typedef __attribute__((ext_vector_type(8))) short short8;
typedef __attribute__((ext_vector_type(4))) float f32x4;

__device__ inline float bf2f(unsigned int bits16){
  union{ unsigned int i; float f; } v; v.i = bits16 << 16; return v.f;
}
__device__ inline unsigned short f2bf_bits(float f){
  __hip_bfloat16 h = __float2bfloat16(f);
  return *reinterpret_cast<unsigned short*>(&h);
}

// ---------------- graph setup kernels ----------------

__global__ void k_deg(const int* __restrict__ src, const int* __restrict__ dst,
                      int* __restrict__ deg, int* __restrict__ indeg){
  int e = blockIdx.x*blockDim.x + threadIdx.x;
  if(e < N_EDGES){
    atomicAdd(&deg[src[e]], 1);
    atomicAdd(&indeg[dst[e]], 1);
  }
}

__global__ void k_dis(const int* __restrict__ deg, float* __restrict__ dis){
  int i = blockIdx.x*blockDim.x + threadIdx.x;
  if(i < N_NODES){
    int d = deg[i];
    dis[i] = d > 0 ? rsqrtf((float)d) : 0.f;
  }
}

__global__ void k_edgew(const int* __restrict__ src, const int* __restrict__ dst,
                        const float* __restrict__ dis, float* __restrict__ w){
  int e = blockIdx.x*blockDim.x + threadIdx.x;
  if(e < N_EDGES){
    w[e] = -dis[src[e]] * dis[dst[e]];
  }
}

__global__ __launch_bounds__(1024) void k_scan(const int* __restrict__ cnt,
                                               int* __restrict__ offs,
                                               int* __restrict__ cursor){
  __shared__ int part[1024];
  const int n = N_NODES;
  const int CH = (n + 1023) / 1024;
  int tid = threadIdx.x;
  int base = tid * CH;
  int s = 0;
  for(int i = 0; i < CH; i++){
    int idx = base + i;
    if(idx < n) s += cnt[idx];
  }
  part[tid] = s;
  __syncthreads();
  for(int off = 1; off < 1024; off <<= 1){
    int v = (tid >= off) ? part[tid - off] : 0;
    __syncthreads();
    part[tid] += v;
    __syncthreads();
  }
  int run = (tid == 0) ? 0 : part[tid - 1];
  for(int i = 0; i < CH; i++){
    int idx = base + i;
    if(idx < n){
      offs[idx] = run;
      cursor[idx] = run;
      run += cnt[idx];
    }
  }
  if(tid == 1023) offs[n] = part[1023];
}

__global__ void k_scatter(const int* __restrict__ src, const int* __restrict__ dst,
                          const float* __restrict__ w, int* __restrict__ cursor,
                          int* __restrict__ csr_s, float* __restrict__ csr_w){
  int e = blockIdx.x*blockDim.x + threadIdx.x;
  if(e < N_EDGES){
    int d = dst[e];
    int p = atomicAdd(&cursor[d], 1);
    csr_s[p] = src[e];
    csr_w[p] = w[e];
  }
}

__global__ __launch_bounds__(128) void k_gbounds(const int* __restrict__ batch,
                                                 int* __restrict__ gstart,
                                                 int* __restrict__ gcnt){
  int g = threadIdx.x;
  if(g <= N_GRAPHS){
    int lo = 0, hi = N_NODES;
    while(lo < hi){
      int mid = (lo + hi) >> 1;
      if(batch[mid] < g) lo = mid + 1; else hi = mid;
    }
    gstart[g] = lo;
  }
  __syncthreads();
  if(g < N_GRAPHS) gcnt[g] = gstart[g + 1] - gstart[g];
}

// ---------------- propagation (frozen: bf16 state, uint4, shfl, MLP=8) ----

__device__ inline void fma8(float* a, uint4 v, float w){
  a[0] += w * bf2f(v.x & 0xffffu); a[1] += w * bf2f(v.x >> 16);
  a[2] += w * bf2f(v.y & 0xffffu); a[3] += w * bf2f(v.y >> 16);
  a[4] += w * bf2f(v.z & 0xffffu); a[5] += w * bf2f(v.z >> 16);
  a[6] += w * bf2f(v.w & 0xffffu); a[7] += w * bf2f(v.w >> 16);
}

__global__ __launch_bounds__(256) void k_prop256(const __hip_bfloat16* __restrict__ Xb,
                                                 const __hip_bfloat16* __restrict__ Pb,
                                                 __hip_bfloat16* __restrict__ tx,
                                                 const int* __restrict__ csr_s,
                                                 const float* __restrict__ csr_w,
                                                 const int* __restrict__ offs,
                                                 float alpha){
  const int stride = KCHEB * C_HID;
  int hl   = threadIdx.x & 31;
  int b32  = threadIdx.x & 32;
  int node = blockIdx.x * 8 + (threadIdx.x >> 5);
  int j0 = offs[node], j1 = offs[node + 1];
  float a[8] = {};
  const __hip_bfloat16* __restrict__ gbase = Xb + hl * 8;
  int j = j0;
  int sv = 0; float wv = 0.f;
  bool have = (j + 7 < j1);
  if(have){ sv = csr_s[j + (hl & 7)]; wv = csr_w[j + (hl & 7)]; }
  while(have){
    int jn = j + 8;
    bool more = (jn + 7 < j1);
    int sv2 = 0; float wv2 = 0.f;
    if(more){ sv2 = csr_s[jn + (hl & 7)]; wv2 = csr_w[jn + (hl & 7)]; }
    uint4 v[8];
#pragma unroll
    for(int i = 0; i < 8; i++){
      int si = __shfl(sv, b32 + i);
      v[i] = *(const uint4*)(gbase + (size_t)si * stride);
    }
#pragma unroll
    for(int i = 0; i < 8; i++){
      float wi = __shfl(wv, b32 + i);
      fma8(a, v[i], wi);
    }
    sv = sv2; wv = wv2; j = jn; have = more;
  }
  for(; j < j1; j++){
    uint4 v0 = *(const uint4*)(gbase + (size_t)csr_s[j] * stride);
    fma8(a, v0, csr_w[j]);
  }
  float r[8];
#pragma unroll
  for(int i = 0; i < 8; i++) r[i] = alpha * a[i];
  size_t off = (size_t)node * stride + hl * 8;
  if(Pb){
    uint4 pv = *(const uint4*)(Pb + off);
    r[0] -= bf2f(pv.x & 0xffffu); r[1] -= bf2f(pv.x >> 16);
    r[2] -= bf2f(pv.y & 0xffffu); r[3] -= bf2f(pv.y >> 16);
    r[4] -= bf2f(pv.z & 0xffffu); r[5] -= bf2f(pv.z >> 16);
    r[6] -= bf2f(pv.w & 0xffffu); r[7] -= bf2f(pv.w >> 16);
  }
  uint4 ob;
  ob.x = (unsigned)f2bf_bits(r[0]) | ((unsigned)f2bf_bits(r[1]) << 16);
  ob.y = (unsigned)f2bf_bits(r[2]) | ((unsigned)f2bf_bits(r[3]) << 16);
  ob.z = (unsigned)f2bf_bits(r[4]) | ((unsigned)f2bf_bits(r[5]) << 16);
  ob.w = (unsigned)f2bf_bits(r[6]) | ((unsigned)f2bf_bits(r[7]) << 16);
  *(uint4*)(tx + off) = ob;
}

__global__ __launch_bounds__(256) void k_prop128(const __hip_bfloat16* __restrict__ Xb,
                                                 const __hip_bfloat16* __restrict__ Pb,
                                                 __hip_bfloat16* __restrict__ tx,
                                                 const int* __restrict__ csr_s,
                                                 const float* __restrict__ csr_w,
                                                 const int* __restrict__ offs,
                                                 float alpha){
  const int stride = KCHEB * C_IN;
  int hl   = threadIdx.x & 31;
  int b32  = threadIdx.x & 32;
  int node = blockIdx.x * 8 + (threadIdx.x >> 5);
  int j0 = offs[node], j1 = offs[node + 1];
  float a[4] = {};
  const __hip_bfloat16* __restrict__ gbase = Xb + hl * 4;
  int j = j0;
  int sv = 0; float wv = 0.f;
  bool have = (j + 7 < j1);
  if(have){ sv = csr_s[j + (hl & 7)]; wv = csr_w[j + (hl & 7)]; }
  while(have){
    int jn = j + 8;
    bool more = (jn + 7 < j1);
    int sv2 = 0; float wv2 = 0.f;
    if(more){ sv2 = csr_s[jn + (hl & 7)]; wv2 = csr_w[jn + (hl & 7)]; }
    uint2 v[8];
#pragma unroll
    for(int i = 0; i < 8; i++){
      int si = __shfl(sv, b32 + i);
      v[i] = *(const uint2*)(gbase + (size_t)si * stride);
    }
#pragma unroll
    for(int i = 0; i < 8; i++){
      float wi = __shfl(wv, b32 + i);
      a[0] += wi * bf2f(v[i].x & 0xffffu); a[1] += wi * bf2f(v[i].x >> 16);
      a[2] += wi * bf2f(v[i].y & 0xffffu); a[3] += wi * bf2f(v[i].y >> 16);
    }
    sv = sv2; wv = wv2; j = jn; have = more;
  }
  for(; j < j1; j++){
    float w0 = csr_w[j];
    uint2 v0 = *(const uint2*)(gbase + (size_t)csr_s[j] * stride);
    a[0] += w0 * bf2f(v0.x & 0xffffu); a[1] += w0 * bf2f(v0.x >> 16);
    a[2] += w0 * bf2f(v0.y & 0xffffu); a[3] += w0 * bf2f(v0.y >> 16);
  }
  float r0 = alpha * a[0], r1 = alpha * a[1], r2 = alpha * a[2], r3 = alpha * a[3];
  size_t off = (size_t)node * stride + hl * 4;
  if(Pb){
    uint2 pv = *(const uint2*)(Pb + off);
    r0 -= bf2f(pv.x & 0xffffu); r1 -= bf2f(pv.x >> 16);
    r2 -= bf2f(pv.y & 0xffffu); r3 -= bf2f(pv.y >> 16);
  }
  uint2 ob;
  ob.x = (unsigned)f2bf_bits(r0) | ((unsigned)f2bf_bits(r1) << 16);
  ob.y = (unsigned)f2bf_bits(r2) | ((unsigned)f2bf_bits(r3) << 16);
  *(uint2*)(tx + off) = ob;
}

// fp32 [rows][C] -> bf16 strided slot (layer-1 input only)
template<int C>
__global__ void k_f2bf(const float* __restrict__ X, __hip_bfloat16* __restrict__ tx,
                       int tx_stride){
  int idx = blockIdx.x * blockDim.x + threadIdx.x;
  const int GPR = C / 4;
  if(idx < N_NODES * GPR){
    int r = idx / GPR;
    int c = (idx - r * GPR) * 4;
    float4 v = *(const float4*)(X + (size_t)r * C + c);
    uint2 ob;
    ob.x = (unsigned)f2bf_bits(v.x) | ((unsigned)f2bf_bits(v.y) << 16);
    ob.y = (unsigned)f2bf_bits(v.z) | ((unsigned)f2bf_bits(v.w) << 16);
    *(uint2*)(tx + (size_t)r * tx_stride + c) = ob;
  }
}

// all three weight transposes in one dispatch: WT[o][kc] = W[kc][o]
__global__ void k_wt3(const float* __restrict__ W0, __hip_bfloat16* __restrict__ WT0,
                      const float* __restrict__ W1, __hip_bfloat16* __restrict__ WT1,
                      const float* __restrict__ W2, __hip_bfloat16* __restrict__ WT2){
  const int n0 = KCHEB * C_IN  * C_HID;   // 327680
  const int n1 = KCHEB * C_HID * C_HID;   // 655360
  int idx = blockIdx.x * blockDim.x + threadIdx.x;
  if(idx < n0){
    int Ktot = KCHEB * C_IN;
    int o = idx / Ktot, kc = idx - o * Ktot;
    WT0[idx] = __float2bfloat16(W0[(size_t)kc * 256 + o]);
  } else if(idx < n0 + n1){
    int i = idx - n0;
    int Ktot = KCHEB * C_HID;
    int o = i / Ktot, kc = i - o * Ktot;
    WT1[i] = __float2bfloat16(W1[(size_t)kc * 256 + o]);
  } else if(idx < n0 + 2 * n1){
    int i = idx - n0 - n1;
    int Ktot = KCHEB * C_HID;
    int o = i / Ktot, kc = i - o * Ktot;
    WT2[i] = __float2bfloat16(W2[(size_t)kc * 256 + o]);
  }
}

// ---------------- MFMA GEMM, XCD-pinned, single-sync double-buffer ----------
// If tx2 != null: write relu(A@B + bias) as bf16 into tx2 (stride K256, slot 0)
// — the next layer's Tx0. Else: write fp32 into H (stride C_HID).

__global__ __launch_bounds__(256) void k_gemm_f(const __hip_bfloat16* __restrict__ A,
                                                const __hip_bfloat16* __restrict__ BT,
                                                const float* __restrict__ bias,
                                                float* __restrict__ H,
                                                __hip_bfloat16* __restrict__ tx2,
                                                int M, int Ktot){
  int b = blockIdx.x;
  int xcd = b & 7;
  int l = b >> 3;
  int m = xcd + 8 * (l >> 2);
  int n = l & 3;
  if(m * 64 >= M) return;
  int row0 = m * 64, col0 = n * 64;

  __shared__ short As[2][64 * 64];
  __shared__ short Bs[2][64 * 64];
  int tid = threadIdx.x;
  int lane = tid & 63;
  int wave = tid >> 6;
  int l15 = lane & 15;
  int quad = lane >> 4;
  int wm = (wave & 1) * 32;
  int wn = (wave >> 1) * 32;

  int e0 = tid, e1 = tid + 256;
  int r0 = e0 >> 3, g0 = e0 & 7;
  int r1 = e1 >> 3, g1 = e1 & 7;
  int gr0 = row0 + r0, gr1 = row0 + r1;
  int sa0 = r0 * 64 + ((g0 ^ (r0 & 7)) * 8);
  int sa1 = r1 * 64 + ((g1 ^ (r1 & 7)) * 8);

  f32x4 acc[2][2] = {};
  uint4 av0, av1, bv0, bv1;

  auto load = [&](int k0){
    av0 = (gr0 < M) ? *(const uint4*)(A + (size_t)gr0 * Ktot + k0 + g0 * 8)
                    : make_uint4(0u, 0u, 0u, 0u);
    av1 = (gr1 < M) ? *(const uint4*)(A + (size_t)gr1 * Ktot + k0 + g1 * 8)
                    : make_uint4(0u, 0u, 0u, 0u);
    bv0 = *(const uint4*)(BT + (size_t)(col0 + r0) * Ktot + k0 + g0 * 8);
    bv1 = *(const uint4*)(BT + (size_t)(col0 + r1) * Ktot + k0 + g1 * 8);
  };
  auto stor = [&](int buf){
    *(uint4*)(&As[buf][sa0]) = av0;
    *(uint4*)(&As[buf][sa1]) = av1;
    *(uint4*)(&Bs[buf][sa0]) = bv0;
    *(uint4*)(&Bs[buf][sa1]) = bv1;
  };

  load(0);
  stor(0);
  __syncthreads();
  int nk = Ktot >> 6;
  for(int it = 0; it < nk; it++){
    int cur = it & 1;
    if(it + 1 < nk) load((it + 1) << 6);   // in flight across MFMAs
#pragma unroll
    for(int kk = 0; kk < 64; kk += 32){
      int g = (kk >> 3) + quad;
      short8 a[2], bb[2];
#pragma unroll
      for(int mi = 0; mi < 2; mi++){
        int r = wm + mi * 16 + l15;
        a[mi] = *(const short8*)(&As[cur][r * 64 + ((g ^ (r & 7)) * 8)]);
      }
#pragma unroll
      for(int ni = 0; ni < 2; ni++){
        int nn = wn + ni * 16 + l15;
        bb[ni] = *(const short8*)(&Bs[cur][nn * 64 + ((g ^ (nn & 7)) * 8)]);
      }
#pragma unroll
      for(int mi = 0; mi < 2; mi++)
#pragma unroll
        for(int ni = 0; ni < 2; ni++)
          acc[mi][ni] = __builtin_amdgcn_mfma_f32_16x16x32_bf16(a[mi], bb[ni], acc[mi][ni], 0, 0, 0);
    }
    if(it + 1 < nk){
      // buf[cur^1]'s last readers finished before the barrier that opened this
      // iteration — safe to overwrite with only ONE barrier per iteration.
      stor(cur ^ 1);
      __syncthreads();
    }
  }

  const int K256 = KCHEB * C_HID;
#pragma unroll
  for(int mi = 0; mi < 2; mi++){
#pragma unroll
    for(int ni = 0; ni < 2; ni++){
      int gcol = col0 + wn + ni * 16 + l15;
      float bv = bias[gcol];
#pragma unroll
      for(int r = 0; r < 4; r++){
        int grow = row0 + wm + mi * 16 + quad * 4 + r;
        if(grow < M){
          float v = fmaxf(acc[mi][ni][r] + bv, 0.f);
          if(tx2) tx2[(size_t)grow * K256 + gcol] = __float2bfloat16(v);
          else    H[(size_t)grow * C_HID + gcol] = v;
        }
      }
    }
  }
}

// ---------------- pooling + head ----------------

__global__ __launch_bounds__(256) void k_pool2(const float* __restrict__ h,
                                               const int* __restrict__ batch,
                                               float* __restrict__ gsum){
  int c  = threadIdx.x;
  int n0 = blockIdx.x * POOL_CHUNK;
  int n1 = n0 + POOL_CHUNK;
  if(n1 > N_NODES) n1 = N_NODES;
  if(n0 >= n1) return;
  float acc = 0.f;
  int cur = batch[n0];
  for(int n = n0; n < n1; n++){
    int g = batch[n];
    if(g != cur){
      atomicAdd(&gsum[cur * C_HID + c], acc);
      acc = 0.f;
      cur = g;
    }
    acc += h[(size_t)n * C_HID + c];
  }
  atomicAdd(&gsum[cur * C_HID + c], acc);
}

__global__ __launch_bounds__(128) void k_final(const float* __restrict__ gsum,
                                               const int* __restrict__ gcnt,
                                               const float* __restrict__ Wout,
                                               const float* __restrict__ bout,
                                               float* __restrict__ out){
  int g = blockIdx.x;
  int o = threadIdx.x;
  float inv = 1.f / fmaxf((float)gcnt[g], 1.f);
  float acc = bout[o];
  for(int c = 0; c < C_HID; c++) acc += gsum[g * C_HID + c] * inv * Wout[c * C_OUTC + o];
  out[g * C_OUTC + o] = acc;
}

// ---------------- host ----------------

extern "C" void kernel_launch(void* const* d_in, const int* in_sizes, int n_in,
                              void* d_out, int out_size, void* d_ws, size_t ws_size,
                              hipStream_t stream){
  const float* x    = (const float*)d_in[0];
  const float* W0   = (const float*)d_in[1];
  const float* b0   = (const float*)d_in[2];
  const float* W1   = (const float*)d_in[3];
  const float* b1   = (const float*)d_in[4];
  const float* W2   = (const float*)d_in[5];
  const float* b2   = (const float*)d_in[6];
  const float* Wout = (const float*)d_in[7];
  const float* bout = (const float*)d_in[8];
  const int*   ei   = (const int*)d_in[9];
  const int*   batch= (const int*)d_in[10];
  const int* src = ei;
  const int* dst = ei + N_EDGES;
  float* out = (float*)d_out;

  char* p = (char*)d_ws;
  auto alloc = [&](size_t bytes)->char*{ char* r = p; p += align_up(bytes, 256); return r; };

  int*   deg    = (int*)  alloc(N_NODES * 4);
  int*   indeg  = (int*)  alloc(N_NODES * 4);
  int*   offs   = (int*)  alloc((N_NODES + 1) * 4);
  int*   cursor = (int*)  alloc(N_NODES * 4);
  float* dis    = (float*)alloc(N_NODES * 4);
  float* w_e    = (float*)alloc(N_EDGES * 4);
  int*   csr_s  = (int*)  alloc(N_EDGES * 4);
  float* csr_w  = (float*)alloc(N_EDGES * 4);
  int*   gcnt   = (int*)  alloc(N_GRAPHS * 4);
  int*   gstart = (int*)  alloc((N_GRAPHS + 1) * 4);
  float* gsum   = (float*)alloc(N_GRAPHS * C_HID * 4);

  const size_t txBytes = (size_t)N_NODES * (KCHEB * C_HID) * 2;  // 51.2 MB
  __hip_bfloat16* txP = (__hip_bfloat16*)alloc(txBytes);
  __hip_bfloat16* txQ = (__hip_bfloat16*)alloc(txBytes);
  __hip_bfloat16* WT0 = (__hip_bfloat16*)alloc((size_t)KCHEB * C_IN  * C_HID * 2);
  __hip_bfloat16* WT1 = (__hip_bfloat16*)alloc((size_t)KCHEB * C_HID * C_HID * 2);
  __hip_bfloat16* WT2 = (__hip_bfloat16*)alloc((size_t)KCHEB * C_HID * C_HID * 2);
  float* Hb = (float*)alloc((size_t)N_NODES * C_HID * 4);

  hipMemsetAsync(deg,   0, N_NODES * 4, stream);
  hipMemsetAsync(indeg, 0, N_NODES * 4, stream);
  hipMemsetAsync(gsum,  0, N_GRAPHS * C_HID * 4, stream);

  const int TB = 256;
  int egrid = (N_EDGES + TB - 1) / TB;
  int ngrid = (N_NODES + TB - 1) / TB;

  k_deg<<<egrid, TB, 0, stream>>>(src, dst, deg, indeg);
  k_dis<<<ngrid, TB, 0, stream>>>(deg, dis);
  k_edgew<<<egrid, TB, 0, stream>>>(src, dst, dis, w_e);
  k_scan<<<1, 1024, 0, stream>>>(indeg, offs, cursor);
  k_scatter<<<egrid, TB, 0, stream>>>(src, dst, w_e, cursor, csr_s, csr_w);
  k_gbounds<<<1, 128, 0, stream>>>(batch, gstart, gcnt);

  {
    int ntot = KCHEB * C_IN * C_HID + 2 * KCHEB * C_HID * C_HID;
    k_wt3<<<(ntot + TB - 1) / TB, TB, 0, stream>>>(W0, WT0, W1, WT1, W2, WT2);
  }

  const int K128 = KCHEB * C_IN;   // 1280
  const int K256 = KCHEB * C_HID;  // 2560
  const int GEMM_BLOCKS = 640;

  // ---- layer 1 (Cin=128, A in txP with stride K128) ----
  {
    int ng = N_NODES * (C_IN / 4);
    k_f2bf<C_IN><<<(ng + TB - 1) / TB, TB, 0, stream>>>(x, txP, K128);
    for(int k = 1; k < KCHEB; k++){
      const __hip_bfloat16* Xb = txP + (size_t)(k - 1) * C_IN;
      const __hip_bfloat16* Pb = (k >= 2) ? txP + (size_t)(k - 2) * C_IN : nullptr;
      __hip_bfloat16* tx = txP + (size_t)k * C_IN;
      k_prop128<<<N_NODES / 8, 256, 0, stream>>>(Xb, Pb, tx, csr_s, csr_w, offs,
                                                 k == 1 ? 1.f : 2.f);
    }
    // GEMM -> bf16 slot 0 of txQ (next layer's A)
    k_gemm_f<<<GEMM_BLOCKS, 256, 0, stream>>>(txP, WT0, b0, nullptr, txQ, N_NODES, K128);
  }

  // ---- layer 2 (A in txQ, stride K256) -> bf16 slot 0 of txP ----
  {
    for(int k = 1; k < KCHEB; k++){
      const __hip_bfloat16* Xb = txQ + (size_t)(k - 1) * C_HID;
      const __hip_bfloat16* Pb = (k >= 2) ? txQ + (size_t)(k - 2) * C_HID : nullptr;
      __hip_bfloat16* tx = txQ + (size_t)k * C_HID;
      k_prop256<<<N_NODES / 8, 256, 0, stream>>>(Xb, Pb, tx, csr_s, csr_w, offs,
                                                 k == 1 ? 1.f : 2.f);
    }
    k_gemm_f<<<GEMM_BLOCKS, 256, 0, stream>>>(txQ, WT1, b1, nullptr, txP, N_NODES, K256);
  }

  // ---- layer 3 (A in txP, stride K256) -> fp32 Hb ----
  {
    for(int k = 1; k < KCHEB; k++){
      const __hip_bfloat16* Xb = txP + (size_t)(k - 1) * C_HID;
      const __hip_bfloat16* Pb = (k >= 2) ? txP + (size_t)(k - 2) * C_HID : nullptr;
      __hip_bfloat16* tx = txP + (size_t)k * C_HID;
      k_prop256<<<N_NODES / 8, 256, 0, stream>>>(Xb, Pb, tx, csr_s, csr_w, offs,
                                                 k == 1 ? 1.f : 2.f);
    }
    k_gemm_f<<<GEMM_BLOCKS, 256, 0, stream>>>(txP, WT2, b2, Hb, nullptr, N_NODES, K256);
  }

  k_pool2<<<(N_NODES + POOL_CHUNK - 1) / POOL_CHUNK, 256, 0, stream>>>(Hb, batch, gsum);
  k_final<<<N_GRAPHS, C_OUTC, 0, stream>>>(gsum, gcnt, Wout, bout, out);
}